// Round 6
// baseline (242.205 us; speedup 1.0000x reference)
//
#include <hip/hip_runtime.h>

typedef __attribute__((ext_vector_type(8))) short short8;
typedef __attribute__((ext_vector_type(8))) unsigned short ushort8;
typedef __attribute__((ext_vector_type(4))) float f32x4;

__device__ __forceinline__ float bf2f(unsigned short u) {
  union { unsigned int u; float f; } c; c.u = ((unsigned int)u) << 16; return c.f;
}
__device__ __forceinline__ unsigned short f2bf(float f) {
  union { float f; unsigned int u; } c; c.f = f;
  unsigned int x = c.u;
  return (unsigned short)((x + 0x7FFFu + ((x >> 16) & 1u)) >> 16);
}

#define GLD_LDS16(g, l)                                                        \
  __builtin_amdgcn_global_load_lds(                                            \
      (const __attribute__((address_space(1))) void*)(g),                      \
      (__attribute__((address_space(3))) void*)(l), 16, 0, 0)

__device__ __forceinline__ void bar() {
  asm volatile("" ::: "memory");
  __builtin_amdgcn_s_barrier();
  asm volatile("" ::: "memory");
}

// --------------------------------------------------- fused prep:
// [0,4096): cast X fp32 -> bf16
// [4096,4864): transpose+cast W[1024][3072] -> Wt[3072][1024] bf16
// 4864: zero Lrow
__global__ __launch_bounds__(256) void prep_kernel(
    const float* __restrict__ X, unsigned short* __restrict__ Xb,
    const float* __restrict__ W, unsigned short* __restrict__ Wt,
    float* __restrict__ Lrow) {
  const int t = threadIdx.x;
  if (blockIdx.x < 4096) {
    long i = ((long)blockIdx.x * 256 + t) * 8;
    float4 a = *(const float4*)(X + i);
    float4 b = *(const float4*)(X + i + 4);
    ushort8 o;
    o[0] = f2bf(a.x); o[1] = f2bf(a.y); o[2] = f2bf(a.z); o[3] = f2bf(a.w);
    o[4] = f2bf(b.x); o[5] = f2bf(b.y); o[6] = f2bf(b.z); o[7] = f2bf(b.w);
    *(ushort8*)(Xb + i) = o;
  } else if (blockIdx.x < 4864) {
    const int bid = blockIdx.x - 4096;          // 768 blocks = 48 x 16
    const int f0 = (bid % 48) * 64;
    const int e0 = (bid / 48) * 64;
    __shared__ unsigned short tile[64][65];
    const int cg = (t & 15) * 4;
    const int r = t >> 4;
#pragma unroll
    for (int i = 0; i < 4; ++i) {
      int e = r + i * 16;
      float4 v = *(const float4*)(W + (long)(e0 + e) * 3072 + f0 + cg);
      tile[e][cg + 0] = f2bf(v.x);
      tile[e][cg + 1] = f2bf(v.y);
      tile[e][cg + 2] = f2bf(v.z);
      tile[e][cg + 3] = f2bf(v.w);
    }
    __syncthreads();
#pragma unroll
    for (int i = 0; i < 4; ++i) {
      int f = (t >> 4) + i * 16;
      int e = (t & 15) * 4;
      ushort4 o;
      o.x = tile[e + 0][f];
      o.y = tile[e + 1][f];
      o.z = tile[e + 2][f];
      o.w = tile[e + 3][f];
      *(ushort4*)(Wt + (long)(f0 + f) * 1024 + e0 + e) = o;
    }
  } else {
    float4 z = {0.f, 0.f, 0.f, 0.f};
#pragma unroll
    for (int j = 0; j < 8; ++j) *(float4*)(Lrow + (j * 256 + t) * 4) = z;
  }
}

// ================================================================
// R6: 256x128 tile, BK=64, 512 threads (8 waves = 4M x 2N, 64x64 each),
// MINIMUM 2-PHASE pipelined loop (catalog T3 recipe): per K-tile ONE
// barrier interval:
//   { issue 6 GLD staging tile T+1 -> nxt;  16 ds_read_b128 frags (T);
//     32 MFMA (compiler-interleaved lgkmcnt); vmcnt(0); bar; swap }
// The vmcnt(0) drain is covered by ~2500 cy of reads+MFMA issued after the
// GLDs (vs m97's exposed stage interval = its documented ~20% stall).
// Perfect grid fill: qkv 24x32=768 blk (3 rounds @1/CU), score 16x8x4=512
// (2 rounds). LDS 96 KiB: 2 bufs x (A[256][64] | B[128][64]), 128 B rows,
// verified XOR-8 slot swizzle (phys slot s of row r = k-chunk s^(r&7);
// linear-dest GLD + pre-swizzled per-lane source col; conflict-free R2-R5).
// Ledger: stage targets nxt, whose last reads were before the PREVIOUS
// bar (reads precede MFMA precede bar) -> safe. Reads of cur were staged
// last iter and collectively landed at last iter's vmcnt(0)+bar -> safe.
// MODE 0 (qkv): bx<16 -> bf16 to QK; bx>=16 -> LDS-transpose -> Vt.
// MODE 1 (score): bf16 exp(acc*alpha) + row-sum atomicAdd into Lrow.
// ================================================================
template <int MODE>
__device__ __forceinline__ void gemm2ph_body(
    const unsigned short* __restrict__ A, const unsigned short* __restrict__ B,
    void* __restrict__ Cv, int K, int lda, int ldb, int ldc,
    long sA, long sB, long sC, float alpha, float* __restrict__ Lrow,
    unsigned short* __restrict__ Vt) {
  __shared__ __align__(16) unsigned short smem[49152];  // 96 KiB

  const int t = threadIdx.x;
  const int lane = t & 63;
  const int wave = t >> 6;        // 0..7
  const int quad = lane >> 4;     // 0..3
  const int mrow = lane & 15;     // 0..15
  const int wm = wave >> 1;       // 0..3  (M quarter, 64 rows)
  const int wn = wave & 1;        // 0..1  (N half, 64 cols)

  const int bx = blockIdx.x, by = blockIdx.y, b = blockIdx.z;
  const int rowA0 = by * 256;
  const int rowB0 = bx * 128;
  const unsigned short* Ab = A + (long)b * sA;
  const unsigned short* Bb = B + (long)b * sB;

  // staging: lane l -> row l>>3, phys slot l&7 holds k-chunk (l&7)^(l>>3)
  const int srow = lane >> 3;
  const int scol = ((lane & 7) ^ srow) * 8;

  // per-GLD global bases; A: 4 x 8-row units, B: 2 units
  const unsigned short* gA[4];
  const unsigned short* gB[2];
#pragma unroll
  for (int g = 0; g < 4; ++g)
    gA[g] = Ab + (long)(rowA0 + wave * 32 + g * 8 + srow) * lda + scol;
#pragma unroll
  for (int g = 0; g < 2; ++g)
    gB[g] = Bb + (long)(rowB0 + wave * 16 + g * 8 + srow) * ldb + scol;
  const int dstA = wave * 2048;          // + g*512, within A region
  const int dstB = 16384 + wave * 1024;  // + g*512, within B region

  f32x4 acc[4][4];
#pragma unroll
  for (int i = 0; i < 4; ++i)
#pragma unroll
    for (int j = 0; j < 4; ++j) {
      f32x4 z = {0.f, 0.f, 0.f, 0.f};
      acc[i][j] = z;
    }

  const int NT = K >> 6;

  // prologue: stage T0 into buf0
#pragma unroll
  for (int g = 0; g < 4; ++g) GLD_LDS16(gA[g], smem + dstA + g * 512);
#pragma unroll
  for (int g = 0; g < 2; ++g) GLD_LDS16(gB[g], smem + dstB + g * 512);
  asm volatile("s_waitcnt vmcnt(0)" ::: "memory");
  bar();

  const int aslot0 = (quad ^ (mrow & 7)) * 8;  // ks=0 slot; ks=1: ^32
  int cur = 0, nxt = 24576;

  for (int T = 0; T < NT; ++T) {
    const int kt1 = (T + 1) << 6;
    // ---- issue next-tile staging first (drains at interval end) ----
    if (T + 1 < NT) {
#pragma unroll
      for (int g = 0; g < 4; ++g)
        GLD_LDS16(gA[g] + kt1, smem + nxt + dstA + g * 512);
#pragma unroll
      for (int g = 0; g < 2; ++g)
        GLD_LDS16(gB[g] + kt1, smem + nxt + dstB + g * 512);
    }
    // ---- fragment reads (compiler interleaves lgkmcnt with MFMA) ----
    short8 a0[4], a1[4], b0[4], b1[4];
#pragma unroll
    for (int i = 0; i < 4; ++i) {
      const int ra = cur + (wm * 64 + i * 16 + mrow) * 64;
      a0[i] = *(const short8*)(smem + ra + aslot0);
      a1[i] = *(const short8*)(smem + ra + (aslot0 ^ 32));
    }
#pragma unroll
    for (int j = 0; j < 4; ++j) {
      const int rb = cur + 16384 + (wn * 64 + j * 16 + mrow) * 64;
      b0[j] = *(const short8*)(smem + rb + aslot0);
      b1[j] = *(const short8*)(smem + rb + (aslot0 ^ 32));
    }
    // ---- 32 MFMA ----
#pragma unroll
    for (int i = 0; i < 4; ++i)
#pragma unroll
      for (int j = 0; j < 4; ++j)
        acc[i][j] = __builtin_amdgcn_mfma_f32_16x16x32_bf16(a0[i], b0[j],
                                                            acc[i][j], 0, 0, 0);
#pragma unroll
    for (int i = 0; i < 4; ++i)
#pragma unroll
      for (int j = 0; j < 4; ++j)
        acc[i][j] = __builtin_amdgcn_mfma_f32_16x16x32_bf16(a1[i], b1[j],
                                                            acc[i][j], 0, 0, 0);
    // ---- tile boundary: staged data landed + visible to all waves ----
    asm volatile("s_waitcnt vmcnt(0)" ::: "memory");
    bar();
    int tmp = cur; cur = nxt; nxt = tmp;
  }

  // -------------------- epilogue --------------------
  const long cb = (long)b * sC;

  if constexpr (MODE == 0) {
    if (bx < 16) {
      unsigned short* C = (unsigned short*)Cv;
#pragma unroll
      for (int i = 0; i < 4; ++i) {
        int row = rowA0 + wm * 64 + i * 16 + quad * 4;
#pragma unroll
        for (int j = 0; j < 4; ++j) {
          int col = rowB0 + wn * 64 + j * 16 + mrow;
#pragma unroll
          for (int r = 0; r < 4; ++r)
            C[(long)(row + r) * ldc + col] = f2bf(acc[i][j][r]);
        }
      }
    } else {
      // V: transpose via LDS (smem reused as [e 128][s 256] bf16, 64 KiB)
      // swz bits 3-6 -> 4-aligned ushort4 writes / 8-aligned ushort8 reads
#pragma unroll
      for (int i = 0; i < 4; ++i) {
        int s4 = wm * 64 + i * 16 + quad * 4;   // tile-local s, 4-aligned
#pragma unroll
        for (int j = 0; j < 4; ++j) {
          int e = wn * 64 + j * 16 + mrow;       // tile-local e (0..127)
          int swz = ((e & 7) << 4) ^ (((e >> 3) & 3) << 3);
          ushort4 pk;
          pk.x = f2bf(acc[i][j][0]);
          pk.y = f2bf(acc[i][j][1]);
          pk.z = f2bf(acc[i][j][2]);
          pk.w = f2bf(acc[i][j][3]);
          *(ushort4*)(smem + e * 256 + (s4 ^ swz)) = pk;
        }
      }
      __syncthreads();
      const int batch = by >> 3;           // by 0..31 -> batch 0..3
      const int s_base = (by & 7) * 256;
      const int e_base = (bx - 16) * 128;
      unsigned short* VtB = Vt + (long)batch * 1024 * 2048;
      const int er = t >> 5;               // 0..15
      const int s = (t & 31) * 8;          // 0..248
#pragma unroll
      for (int rnd = 0; rnd < 8; ++rnd) {
        int e = rnd * 16 + er;             // 0..127
        int swz = ((e & 7) << 4) ^ (((e >> 3) & 3) << 3);
        ushort8 v = *(const ushort8*)(smem + e * 256 + (s ^ swz));
        *(ushort8*)(VtB + (long)(e_base + e) * 2048 + s_base + s) = v;
      }
    }
  } else {
    // MODE 1: E = exp(acc*alpha) -> bf16; row sums -> Lrow
    unsigned short* C = (unsigned short*)Cv;
    float p[4][4];
#pragma unroll
    for (int i = 0; i < 4; ++i)
#pragma unroll
      for (int r = 0; r < 4; ++r) p[i][r] = 0.f;
#pragma unroll
    for (int i = 0; i < 4; ++i) {
      int row = rowA0 + wm * 64 + i * 16 + quad * 4;
#pragma unroll
      for (int j = 0; j < 4; ++j) {
        int col = rowB0 + wn * 64 + j * 16 + mrow;
#pragma unroll
        for (int r = 0; r < 4; ++r) {
          float e = __expf(acc[i][j][r] * alpha);
          C[cb + (long)(row + r) * ldc + col] = f2bf(e);
          p[i][r] += e;
        }
      }
    }
#pragma unroll
    for (int off = 1; off < 16; off <<= 1)
#pragma unroll
      for (int i = 0; i < 4; ++i)
#pragma unroll
        for (int r = 0; r < 4; ++r)
          p[i][r] += __shfl_xor(p[i][r], off, 64);
    if (mrow == 0) {
#pragma unroll
      for (int i = 0; i < 4; ++i) {
        int row = rowA0 + wm * 64 + i * 16 + quad * 4;
#pragma unroll
        for (int r = 0; r < 4; ++r)
          atomicAdd(&Lrow[b * 2048 + row + r], p[i][r]);
      }
    }
  }
}

// ---------------------------------------------------------------- m97 body,
// kept for the out GEMM (MODE 2 only: fp32 store of acc/Lrow[row]).
template <int MODE>
__device__ __forceinline__ void gemm_body(
    const unsigned short* __restrict__ A, const unsigned short* __restrict__ B,
    void* __restrict__ Cv, int K, int lda, int ldb, int ldc,
    long sA, long sB, long sC, float alpha, float* __restrict__ Lrow,
    unsigned short* __restrict__ Vt) {
  constexpr int BM = 128, BN = 128, BK = 64;
  __shared__ __align__(16) unsigned short smem[BM * BK + BN * BK];  // 32 KB
  unsigned short* As = smem;
  unsigned short* Bs = smem + BM * BK;

  const int t = threadIdx.x;
  const int lane = t & 63;
  const int wave = t >> 6;
  const int quad = lane >> 4;
  const int mrow = lane & 15;
  const int wm = wave >> 1, wn = wave & 1;

  const int bx = blockIdx.x, by = blockIdx.y;
  const int rowA0 = by * BM;
  const int rowB0 = bx * BN;
  const int b = blockIdx.z;
  const unsigned short* Ab = A + (long)b * sA;
  const unsigned short* Bb = B + (long)b * sB;

  f32x4 acc[4][4];
#pragma unroll
  for (int i = 0; i < 4; ++i)
#pragma unroll
    for (int j = 0; j < 4; ++j) {
      f32x4 z = {0.f, 0.f, 0.f, 0.f};
      acc[i][j] = z;
    }

  const int rbase = wave * 32 + (lane >> 3);
  const int c2 = lane & 7;

  for (int kt = 0; kt < K; kt += BK) {
#pragma unroll
    for (int j = 0; j < 4; ++j) {
      int r = rbase + j * 8;
      int c = c2 ^ (r & 7);
      GLD_LDS16(Ab + (long)(rowA0 + r) * lda + kt + c * 8, As + (wave * 4 + j) * 512);
      GLD_LDS16(Bb + (long)(rowB0 + r) * ldb + kt + c * 8, Bs + (wave * 4 + j) * 512);
    }
    __syncthreads();
#pragma unroll
    for (int ks = 0; ks < 2; ++ks) {
      short8 af[4], bfr[4];
#pragma unroll
      for (int i = 0; i < 4; ++i) {
        int rA = wm * 64 + i * 16 + mrow;
        int cc = ks * 4 + quad;
        af[i] = *(const short8*)(As + (rA * 8 + (cc ^ (rA & 7))) * 8);
        int rB = wn * 64 + i * 16 + mrow;
        bfr[i] = *(const short8*)(Bs + (rB * 8 + (cc ^ (rB & 7))) * 8);
      }
#pragma unroll
      for (int mt = 0; mt < 4; ++mt)
#pragma unroll
        for (int nt = 0; nt < 4; ++nt)
          acc[mt][nt] = __builtin_amdgcn_mfma_f32_16x16x32_bf16(
              af[mt], bfr[nt], acc[mt][nt], 0, 0, 0);
    }
    __syncthreads();
  }

  const int m_base = rowA0 + wm * 64;
  const int n_base = rowB0 + wn * 64;
  const long cb = (long)b * sC;

  // MODE 2 only instantiated: fp32 out, scaled by 1/Lrow[row]
#pragma unroll
  for (int mt = 0; mt < 4; ++mt)
#pragma unroll
    for (int i = 0; i < 4; ++i) {
      int row = m_base + mt * 16 + quad * 4 + i;
      float inv = 1.0f / Lrow[b * 2048 + row];
#pragma unroll
      for (int nt = 0; nt < 4; ++nt) {
        int col = n_base + nt * 16 + mrow;
        ((float*)Cv)[cb + (long)row * ldc + col] = acc[mt][nt][i] * inv;
      }
    }
}

// distinct names so rocprof separates the three GEMMs
__global__ __launch_bounds__(512, 2) void qkv_gemm_kernel(
    const unsigned short* __restrict__ A, const unsigned short* __restrict__ B,
    void* __restrict__ Cv, int K, int lda, int ldb, int ldc,
    long sA, long sB, long sC, float alpha, float* __restrict__ Lrow,
    unsigned short* __restrict__ Vt) {
  gemm2ph_body<0>(A, B, Cv, K, lda, ldb, ldc, sA, sB, sC, alpha, Lrow, Vt);
}
__global__ __launch_bounds__(512, 2) void score_gemm_kernel(
    const unsigned short* __restrict__ A, const unsigned short* __restrict__ B,
    void* __restrict__ Cv, int K, int lda, int ldb, int ldc,
    long sA, long sB, long sC, float alpha, float* __restrict__ Lrow,
    unsigned short* __restrict__ Vt) {
  gemm2ph_body<1>(A, B, Cv, K, lda, ldb, ldc, sA, sB, sC, alpha, Lrow, Vt);
}
__global__ __launch_bounds__(256, 2) void out_gemm_kernel(
    const unsigned short* __restrict__ A, const unsigned short* __restrict__ B,
    void* __restrict__ Cv, int K, int lda, int ldb, int ldc,
    long sA, long sB, long sC, float alpha, float* __restrict__ Lrow,
    unsigned short* __restrict__ Vt) {
  gemm_body<2>(A, B, Cv, K, lda, ldb, ldc, sA, sB, sC, alpha, Lrow, Vt);
}

// ---------------------------------------------------------------- launch
extern "C" void kernel_launch(void* const* d_in, const int* in_sizes, int n_in,
                              void* d_out, int out_size, void* d_ws, size_t ws_size,
                              hipStream_t stream) {
  const float* X = (const float*)d_in[0];  // [4,2048,1024] fp32
  const float* W = (const float*)d_in[1];  // [1024,3072] fp32
  float* out = (float*)d_out;              // [4,2048,1024] fp32

  char* ws = (char*)d_ws;
  unsigned short* Xb  = (unsigned short*)(ws);                 // 8192x1024 bf16   (16 MiB)
  unsigned short* Wtb = (unsigned short*)(ws + 16777216);      // 3072x1024 bf16   ( 6 MiB)
  unsigned short* QK  = (unsigned short*)(ws + 23068672);      // 8192x2048 bf16   (32 MiB)
  unsigned short* Vt  = (unsigned short*)(ws + 56623104);      // 4x1024x2048 bf16 (16 MiB)
  unsigned short* Sb  = (unsigned short*)(ws + 73400320);      // 4x2048x2048 bf16 (32 MiB)
  float* Lrow         = (float*)(ws + 106954752);              // 4x2048 fp32      (32 KiB)

  // 1. prep: cast X, transpose W, zero Lrow
  prep_kernel<<<4865, 256, 0, stream>>>(X, Xb, W, Wtb, Lrow);

  // 2. [Q|K] = Xb @ Wtb^T  (bx<16 -> QK, ldc=2048); V -> Vt transposed (bx>=16)
  //    256x128 tiles: 24 x 32 = 768 blocks = 3 exact rounds @ 1 blk/CU
  qkv_gemm_kernel<<<dim3(24, 32, 1), 512, 0, stream>>>(
      Xb, Wtb, QK, 1024, 1024, 1024, 2048, 0L, 0L, 0L, 1.0f, nullptr, Vt);

  // 3. E = exp(Q @ K^T / 32) per batch [2048 x 2048], K=1024; row sums -> Lrow
  //    16 x 8 x 4 = 512 blocks = 2 exact rounds
  score_gemm_kernel<<<dim3(16, 8, 4), 512, 0, stream>>>(
      QK, QK + 1024, Sb, 1024, 2048, 2048, 2048,
      (long)2048 * 2048, (long)2048 * 2048, (long)2048 * 2048, 0.03125f, Lrow, nullptr);

  // 4. O = (E @ Vt^T) / L  per batch  [2048 x 1024], K=2048 -> fp32 out
  out_gemm_kernel<<<dim3(8, 16, 4), 256, 0, stream>>>(
      Sb, Vt, out, 2048, 2048, 2048, 1024,
      (long)2048 * 2048, (long)1024 * 2048, (long)2048 * 1024, 1.0f, Lrow, nullptr);
}

// Round 7
// 232.241 us; speedup vs baseline: 1.0429x; 1.0429x over previous
//
#include <hip/hip_runtime.h>

typedef __attribute__((ext_vector_type(8))) short short8;
typedef __attribute__((ext_vector_type(8))) unsigned short ushort8;
typedef __attribute__((ext_vector_type(4))) float f32x4;

__device__ __forceinline__ float bf2f(unsigned short u) {
  union { unsigned int u; float f; } c; c.u = ((unsigned int)u) << 16; return c.f;
}
__device__ __forceinline__ unsigned short f2bf(float f) {
  union { float f; unsigned int u; } c; c.f = f;
  unsigned int x = c.u;
  return (unsigned short)((x + 0x7FFFu + ((x >> 16) & 1u)) >> 16);
}

#define GLD_LDS16(g, l)                                                        \
  __builtin_amdgcn_global_load_lds(                                            \
      (const __attribute__((address_space(1))) void*)(g),                      \
      (__attribute__((address_space(3))) void*)(l), 16, 0, 0)

__device__ __forceinline__ void bar() {
  asm volatile("" ::: "memory");
  __builtin_amdgcn_s_barrier();
  asm volatile("" ::: "memory");
}

// --------------------------------------------------- fused prep:
// [0,4096): cast X fp32 -> bf16
// [4096,4864): transpose+cast W[1024][3072] -> Wt[3072][1024] bf16
// 4864: zero Lrow
__global__ __launch_bounds__(256) void prep_kernel(
    const float* __restrict__ X, unsigned short* __restrict__ Xb,
    const float* __restrict__ W, unsigned short* __restrict__ Wt,
    float* __restrict__ Lrow) {
  const int t = threadIdx.x;
  if (blockIdx.x < 4096) {
    long i = ((long)blockIdx.x * 256 + t) * 8;
    float4 a = *(const float4*)(X + i);
    float4 b = *(const float4*)(X + i + 4);
    ushort8 o;
    o[0] = f2bf(a.x); o[1] = f2bf(a.y); o[2] = f2bf(a.z); o[3] = f2bf(a.w);
    o[4] = f2bf(b.x); o[5] = f2bf(b.y); o[6] = f2bf(b.z); o[7] = f2bf(b.w);
    *(ushort8*)(Xb + i) = o;
  } else if (blockIdx.x < 4864) {
    const int bid = blockIdx.x - 4096;          // 768 blocks = 48 x 16
    const int f0 = (bid % 48) * 64;
    const int e0 = (bid / 48) * 64;
    __shared__ unsigned short tile[64][65];
    const int cg = (t & 15) * 4;
    const int r = t >> 4;
#pragma unroll
    for (int i = 0; i < 4; ++i) {
      int e = r + i * 16;
      float4 v = *(const float4*)(W + (long)(e0 + e) * 3072 + f0 + cg);
      tile[e][cg + 0] = f2bf(v.x);
      tile[e][cg + 1] = f2bf(v.y);
      tile[e][cg + 2] = f2bf(v.z);
      tile[e][cg + 3] = f2bf(v.w);
    }
    __syncthreads();
#pragma unroll
    for (int i = 0; i < 4; ++i) {
      int f = (t >> 4) + i * 16;
      int e = (t & 15) * 4;
      ushort4 o;
      o.x = tile[e + 0][f];
      o.y = tile[e + 1][f];
      o.z = tile[e + 2][f];
      o.w = tile[e + 3][f];
      *(ushort4*)(Wt + (long)(f0 + f) * 1024 + e0 + e) = o;
    }
  } else {
    float4 z = {0.f, 0.f, 0.f, 0.f};
#pragma unroll
    for (int j = 0; j < 8; ++j) *(float4*)(Lrow + (j * 256 + t) * 4) = z;
  }
}

// ---------------------------------------------------------------- m97 body
// (R0-verified: qkv 60.9 us, 844 TF at 2 blk/CU, 3 exact rounds).
// MODE 0 (qkv): bx<16 -> bf16 C to QK; bx>=16 -> transposed bf16 to Vt.
// MODE 2 (out): fp32 store of acc/Lrow[row].
template <int MODE>
__device__ __forceinline__ void gemm_body(
    const unsigned short* __restrict__ A, const unsigned short* __restrict__ B,
    void* __restrict__ Cv, int K, int lda, int ldb, int ldc,
    long sA, long sB, long sC, float alpha, float* __restrict__ Lrow,
    unsigned short* __restrict__ Vt) {
  constexpr int BM = 128, BN = 128, BK = 64;
  __shared__ __align__(16) unsigned short smem[BM * BK + BN * BK];  // 32 KB
  unsigned short* As = smem;
  unsigned short* Bs = smem + BM * BK;

  const int t = threadIdx.x;
  const int lane = t & 63;
  const int wave = t >> 6;
  const int quad = lane >> 4;
  const int mrow = lane & 15;
  const int wm = wave >> 1, wn = wave & 1;

  const int bx = blockIdx.x, by = blockIdx.y;
  const int rowA0 = by * BM;
  const int rowB0 = bx * BN;
  const int b = blockIdx.z;
  const unsigned short* Ab = A + (long)b * sA;
  const unsigned short* Bb = B + (long)b * sB;

  f32x4 acc[4][4];
#pragma unroll
  for (int i = 0; i < 4; ++i)
#pragma unroll
    for (int j = 0; j < 4; ++j) {
      f32x4 z = {0.f, 0.f, 0.f, 0.f};
      acc[i][j] = z;
    }

  const int rbase = wave * 32 + (lane >> 3);
  const int c2 = lane & 7;

  for (int kt = 0; kt < K; kt += BK) {
#pragma unroll
    for (int j = 0; j < 4; ++j) {
      int r = rbase + j * 8;
      int c = c2 ^ (r & 7);
      GLD_LDS16(Ab + (long)(rowA0 + r) * lda + kt + c * 8, As + (wave * 4 + j) * 512);
      GLD_LDS16(Bb + (long)(rowB0 + r) * ldb + kt + c * 8, Bs + (wave * 4 + j) * 512);
    }
    __syncthreads();
#pragma unroll
    for (int ks = 0; ks < 2; ++ks) {
      short8 af[4], bfr[4];
#pragma unroll
      for (int i = 0; i < 4; ++i) {
        int rA = wm * 64 + i * 16 + mrow;
        int cc = ks * 4 + quad;
        af[i] = *(const short8*)(As + (rA * 8 + (cc ^ (rA & 7))) * 8);
        int rB = wn * 64 + i * 16 + mrow;
        bfr[i] = *(const short8*)(Bs + (rB * 8 + (cc ^ (rB & 7))) * 8);
      }
#pragma unroll
      for (int mt = 0; mt < 4; ++mt)
#pragma unroll
        for (int nt = 0; nt < 4; ++nt)
          acc[mt][nt] = __builtin_amdgcn_mfma_f32_16x16x32_bf16(
              af[mt], bfr[nt], acc[mt][nt], 0, 0, 0);
    }
    __syncthreads();
  }

  // epilogue — C/D layout (m89-verified): col = lane&15, row = quad*4 + reg
  const int m_base = rowA0 + wm * 64;
  const int n_base = rowB0 + wn * 64;
  const long cb = (long)b * sC;

  if constexpr (MODE == 0) {
    if (bx < 16) {
      // Q/K columns: plain bf16 write into QK
#pragma unroll
      for (int mt = 0; mt < 4; ++mt)
#pragma unroll
        for (int nt = 0; nt < 4; ++nt)
#pragma unroll
          for (int i = 0; i < 4; ++i) {
            int row = m_base + mt * 16 + quad * 4 + i;
            int col = n_base + nt * 16 + mrow;
            ((unsigned short*)Cv)[cb + (long)row * ldc + col] = f2bf(acc[mt][nt][i]);
          }
    } else {
      // V columns: transpose via LDS (smem = full 128x128 bf16 tile), write Vt.
      // swz(x) = ((x&7)<<4) ^ (((x>>3)&3)<<3) — bits >=3 only, so 4-aligned
      // ushort4 writes and 8-aligned ushort8 reads stay contiguous.
#pragma unroll
      for (int mt = 0; mt < 4; ++mt)
#pragma unroll
        for (int nt = 0; nt < 4; ++nt) {
          int r4 = wm * 64 + mt * 16 + quad * 4;         // 4-aligned tile-local s
          int cL = wn * 64 + nt * 16 + mrow;             // tile-local e
          int swz = ((cL & 7) << 4) ^ (((cL >> 3) & 3) << 3);
          ushort4 pk;
          pk.x = f2bf(acc[mt][nt][0]);
          pk.y = f2bf(acc[mt][nt][1]);
          pk.z = f2bf(acc[mt][nt][2]);
          pk.w = f2bf(acc[mt][nt][3]);
          *(ushort4*)(smem + cL * 128 + (r4 ^ swz)) = pk;
        }
      __syncthreads();
      const int batch = by >> 4;
      const int s_base = (by & 15) * 128;
      const int e_base = (bx - 16) * 128;
      unsigned short* VtB = Vt + (long)batch * 1024 * 2048;
#pragma unroll
      for (int rnd = 0; rnd < 8; ++rnd) {
        int e = (t >> 4) + rnd * 16;
        int s = (t & 15) * 8;
        int swz = ((e & 7) << 4) ^ (((e >> 3) & 3) << 3);
        ushort8 v = *(const ushort8*)(smem + e * 128 + (s ^ swz));
        *(ushort8*)(VtB + (long)(e_base + e) * 2048 + s_base + s) = v;
      }
    }
  } else {
    // MODE 2: fp32 out, scaled by 1/Lrow[row]
#pragma unroll
    for (int mt = 0; mt < 4; ++mt)
#pragma unroll
      for (int i = 0; i < 4; ++i) {
        int row = m_base + mt * 16 + quad * 4 + i;
        float inv = 1.0f / Lrow[b * 2048 + row];
#pragma unroll
        for (int nt = 0; nt < 4; ++nt) {
          int col = n_base + nt * 16 + mrow;
          ((float*)Cv)[cb + (long)row * ldc + col] = acc[mt][nt][i] * inv;
        }
      }
  }
}

// ================================================================
// R5 4-phase 256x256 body (R5-verified correct; block-rate ~1009 TF).
// Used ONLY for score at its perfect-fill grid (8,8,4) = 256 blocks = 1
// round at 1 blk/CU. Per phase: {reads; 1 half-stage; bar; lgkm(0);
// setprio MFMA}; one vmcnt+bar per tile. See R5 ledger.
// MODE 1 (score): bf16 exp(acc*alpha) + row-sum atomicAdd into Lrow.
// ================================================================
template <int MODE>
__device__ __forceinline__ void gemm256_body(
    const unsigned short* __restrict__ A, const unsigned short* __restrict__ B,
    void* __restrict__ Cv, int K, int lda, int ldb, int ldc,
    long sA, long sB, long sC, float alpha, float* __restrict__ Lrow,
    unsigned short* __restrict__ Vt) {
  __shared__ __align__(16) unsigned short smem[65536];  // 128 KiB

  const int t = threadIdx.x;
  const int lane = t & 63;
  const int wave = t >> 6;        // 0..7
  const int quad = lane >> 4;     // 0..3
  const int mrow = lane & 15;     // 0..15
  const int wm = wave >> 2;       // 0..1  (M half)
  const int wn = wave & 3;        // 0..3  (N quarter)

  const int bx = blockIdx.x, by = blockIdx.y, b = blockIdx.z;
  const int rowA0 = by * 256;
  const int rowB0 = bx * 256;
  const unsigned short* Ab = A + (long)b * sA;
  const unsigned short* Bb = B + (long)b * sB;

  const int srow = lane >> 3;
  const int scol = ((lane & 7) ^ srow) * 8;

  const unsigned short* gA[2][2];
  const unsigned short* gB[2][2];
#pragma unroll
  for (int h = 0; h < 2; ++h)
#pragma unroll
    for (int g = 0; g < 2; ++g) {
      gA[h][g] =
          Ab + (long)(rowA0 + h * 128 + wave * 16 + g * 8 + srow) * lda + scol;
      gB[h][g] =
          Bb + (long)(rowB0 + h * 128 + wave * 16 + g * 8 + srow) * ldb + scol;
    }
  const int dsth = wave * 1024;

  f32x4 acc[8][4];
#pragma unroll
  for (int i = 0; i < 8; ++i)
#pragma unroll
    for (int j = 0; j < 4; ++j) {
      f32x4 z = {0.f, 0.f, 0.f, 0.f};
      acc[i][j] = z;
    }

  const int NT = K >> 6;

  auto stgA = [&](int h, int kt, int boff) {
    GLD_LDS16(gA[h][0] + kt, smem + boff + h * 8192 + dsth);
    GLD_LDS16(gA[h][1] + kt, smem + boff + h * 8192 + dsth + 512);
  };
  auto stgB = [&](int h, int kt, int boff) {
    GLD_LDS16(gB[h][0] + kt, smem + boff + 16384 + h * 8192 + dsth);
    GLD_LDS16(gB[h][1] + kt, smem + boff + 16384 + h * 8192 + dsth + 512);
  };

  // prologue: T0 fully; B-h0(T1) into buf1
  stgA(0, 0, 0);
  stgA(1, 0, 0);
  stgB(0, 0, 0);
  stgB(1, 0, 0);
  if (NT > 1) {
    stgB(0, 64, 32768);
    asm volatile("s_waitcnt vmcnt(2)" ::: "memory");
  } else {
    asm volatile("s_waitcnt vmcnt(0)" ::: "memory");
  }
  bar();

  const int aslot0 = (quad ^ (mrow & 7)) * 8;
  const int arow0 = (wm * 128 + mrow) * 64;
  const int brow0 = (wn * 64 + mrow) * 64;

  int cur = 0, nxt = 32768;
  short8 aC[4], bC[4];

  for (int T = 0; T < NT; ++T) {
    const unsigned short* As = smem + cur;
    const unsigned short* Bs = smem + cur + 16384;
    const int kt1 = (T + 1) << 6;
    const int kt2 = (T + 2) << 6;
    const bool m1 = (T + 1) < NT;
    const bool m2 = (T + 2) < NT;

    // p0
#pragma unroll
    for (int i = 0; i < 4; ++i)
      aC[i] = *(const short8*)(As + arow0 + i * 1024 + aslot0);
#pragma unroll
    for (int j = 0; j < 4; ++j)
      bC[j] = *(const short8*)(Bs + brow0 + j * 1024 + aslot0);
    if (m1) stgA(0, kt1, nxt);
    bar();
    asm volatile("s_waitcnt lgkmcnt(0)" ::: "memory");
    __builtin_amdgcn_sched_barrier(0);
    __builtin_amdgcn_s_setprio(1);
#pragma unroll
    for (int i = 0; i < 4; ++i)
#pragma unroll
      for (int j = 0; j < 4; ++j)
        acc[i][j] = __builtin_amdgcn_mfma_f32_16x16x32_bf16(aC[i], bC[j],
                                                            acc[i][j], 0, 0, 0);
    __builtin_amdgcn_s_setprio(0);
    __builtin_amdgcn_sched_barrier(0);

    // p1
#pragma unroll
    for (int i = 0; i < 4; ++i)
      aC[i] = *(const short8*)(As + arow0 + 4096 + i * 1024 + aslot0);
    if (m1) stgA(1, kt1, nxt);
    bar();
    asm volatile("s_waitcnt lgkmcnt(0)" ::: "memory");
    __builtin_amdgcn_sched_barrier(0);
    __builtin_amdgcn_s_setprio(1);
#pragma unroll
    for (int i = 0; i < 4; ++i)
#pragma unroll
      for (int j = 0; j < 4; ++j)
        acc[4 + i][j] = __builtin_amdgcn_mfma_f32_16x16x32_bf16(
            aC[i], bC[j], acc[4 + i][j], 0, 0, 0);
    __builtin_amdgcn_s_setprio(0);
    __builtin_amdgcn_sched_barrier(0);

    // p2
#pragma unroll
    for (int i = 0; i < 4; ++i)
      aC[i] = *(const short8*)(As + arow0 + i * 1024 + (aslot0 ^ 32));
#pragma unroll
    for (int j = 0; j < 4; ++j)
      bC[j] = *(const short8*)(Bs + brow0 + j * 1024 + (aslot0 ^ 32));
    if (m1) stgB(1, kt1, nxt);
    bar();
    asm volatile("s_waitcnt lgkmcnt(0)" ::: "memory");
    __builtin_amdgcn_sched_barrier(0);
    __builtin_amdgcn_s_setprio(1);
#pragma unroll
    for (int i = 0; i < 4; ++i)
#pragma unroll
      for (int j = 0; j < 4; ++j)
        acc[i][j] = __builtin_amdgcn_mfma_f32_16x16x32_bf16(aC[i], bC[j],
                                                            acc[i][j], 0, 0, 0);
    __builtin_amdgcn_s_setprio(0);
    __builtin_amdgcn_sched_barrier(0);

    // p3
#pragma unroll
    for (int i = 0; i < 4; ++i)
      aC[i] = *(const short8*)(As + arow0 + 4096 + i * 1024 + (aslot0 ^ 32));
    if (m2) stgB(0, kt2, cur);
    bar();
    asm volatile("s_waitcnt lgkmcnt(0)" ::: "memory");
    __builtin_amdgcn_sched_barrier(0);
    __builtin_amdgcn_s_setprio(1);
#pragma unroll
    for (int i = 0; i < 4; ++i)
#pragma unroll
      for (int j = 0; j < 4; ++j)
        acc[4 + i][j] = __builtin_amdgcn_mfma_f32_16x16x32_bf16(
            aC[i], bC[j], acc[4 + i][j], 0, 0, 0);
    __builtin_amdgcn_s_setprio(0);
    __builtin_amdgcn_sched_barrier(0);
    if (m2) {
      asm volatile("s_waitcnt vmcnt(2)" ::: "memory");
    } else {
      asm volatile("s_waitcnt vmcnt(0)" ::: "memory");
    }
    bar();

    int tmp = cur; cur = nxt; nxt = tmp;
  }

  // epilogue (MODE 1 only instantiated): E = exp(acc*alpha); rowsum -> Lrow
  const long cb = (long)b * sC;
  {
    unsigned short* C = (unsigned short*)Cv;
    float p[8][4];
#pragma unroll
    for (int m = 0; m < 8; ++m)
#pragma unroll
      for (int r = 0; r < 4; ++r) p[m][r] = 0.f;
#pragma unroll
    for (int m = 0; m < 8; ++m) {
      int row = rowA0 + wm * 128 + m * 16 + quad * 4;
#pragma unroll
      for (int j = 0; j < 4; ++j) {
        int col = rowB0 + wn * 64 + j * 16 + mrow;
#pragma unroll
        for (int r = 0; r < 4; ++r) {
          float e = __expf(acc[m][j][r] * alpha);
          C[cb + (long)(row + r) * ldc + col] = f2bf(e);
          p[m][r] += e;
        }
      }
    }
#pragma unroll
    for (int off = 1; off < 16; off <<= 1)
#pragma unroll
      for (int m = 0; m < 8; ++m)
#pragma unroll
        for (int r = 0; r < 4; ++r)
          p[m][r] += __shfl_xor(p[m][r], off, 64);
    if (mrow == 0) {
#pragma unroll
      for (int m = 0; m < 8; ++m) {
        int row = rowA0 + wm * 128 + m * 16 + quad * 4;
#pragma unroll
        for (int r = 0; r < 4; ++r)
          atomicAdd(&Lrow[b * 2048 + row + r], p[m][r]);
      }
    }
  }
}

// distinct names so rocprof separates the three GEMMs
__global__ __launch_bounds__(256, 2) void qkv_gemm_kernel(
    const unsigned short* __restrict__ A, const unsigned short* __restrict__ B,
    void* __restrict__ Cv, int K, int lda, int ldb, int ldc,
    long sA, long sB, long sC, float alpha, float* __restrict__ Lrow,
    unsigned short* __restrict__ Vt) {
  gemm_body<0>(A, B, Cv, K, lda, ldb, ldc, sA, sB, sC, alpha, Lrow, Vt);
}
__global__ __launch_bounds__(512, 2) void score_gemm_kernel(
    const unsigned short* __restrict__ A, const unsigned short* __restrict__ B,
    void* __restrict__ Cv, int K, int lda, int ldb, int ldc,
    long sA, long sB, long sC, float alpha, float* __restrict__ Lrow,
    unsigned short* __restrict__ Vt) {
  gemm256_body<1>(A, B, Cv, K, lda, ldb, ldc, sA, sB, sC, alpha, Lrow, Vt);
}
__global__ __launch_bounds__(256, 2) void out_gemm_kernel(
    const unsigned short* __restrict__ A, const unsigned short* __restrict__ B,
    void* __restrict__ Cv, int K, int lda, int ldb, int ldc,
    long sA, long sB, long sC, float alpha, float* __restrict__ Lrow,
    unsigned short* __restrict__ Vt) {
  gemm_body<2>(A, B, Cv, K, lda, ldb, ldc, sA, sB, sC, alpha, Lrow, Vt);
}

// ---------------------------------------------------------------- launch
extern "C" void kernel_launch(void* const* d_in, const int* in_sizes, int n_in,
                              void* d_out, int out_size, void* d_ws, size_t ws_size,
                              hipStream_t stream) {
  const float* X = (const float*)d_in[0];  // [4,2048,1024] fp32
  const float* W = (const float*)d_in[1];  // [1024,3072] fp32
  float* out = (float*)d_out;              // [4,2048,1024] fp32

  char* ws = (char*)d_ws;
  unsigned short* Xb  = (unsigned short*)(ws);                 // 8192x1024 bf16   (16 MiB)
  unsigned short* Wtb = (unsigned short*)(ws + 16777216);      // 3072x1024 bf16   ( 6 MiB)
  unsigned short* QK  = (unsigned short*)(ws + 23068672);      // 8192x2048 bf16   (32 MiB)
  unsigned short* Vt  = (unsigned short*)(ws + 56623104);      // 4x1024x2048 bf16 (16 MiB)
  unsigned short* Sb  = (unsigned short*)(ws + 73400320);      // 4x2048x2048 bf16 (32 MiB)
  float* Lrow         = (float*)(ws + 106954752);              // 4x2048 fp32      (32 KiB)

  // 1. prep: cast X, transpose W, zero Lrow
  prep_kernel<<<4865, 256, 0, stream>>>(X, Xb, W, Wtb, Lrow);

  // 2. [Q|K] = Xb @ Wtb^T  (m97 128^2, 24x64 = 1536 blk = 3 exact rounds @2/CU;
  //    bx<16 -> QK, ldc=2048; bx>=16 -> Vt transposed)  [R0: 60.9 us]
  qkv_gemm_kernel<<<dim3(24, 64, 1), 256, 0, stream>>>(
      Xb, Wtb, QK, 1024, 1024, 1024, 2048, 0L, 0L, 0L, 1.0f, nullptr, Vt);

  // 3. E = exp(Q @ K^T / 32) per batch, K=1024; row sums -> Lrow
  //    R5 4-phase 256^2 body at PERFECT FILL: 8x8x4 = 256 blocks = 1 round
  score_gemm_kernel<<<dim3(8, 8, 4), 512, 0, stream>>>(
      QK, QK + 1024, Sb, 1024, 2048, 2048, 2048,
      (long)2048 * 2048, (long)2048 * 2048, (long)2048 * 2048, 0.03125f, Lrow, nullptr);

  // 4. O = (E @ Vt^T) / L  per batch  [2048 x 1024], K=2048 -> fp32 out
  //    m97, 8x16x4 = 512 blocks = 1 exact round @2/CU
  out_gemm_kernel<<<dim3(8, 16, 4), 256, 0, stream>>>(
      Sb, Vt, out, 2048, 2048, 2048, 1024,
      (long)2048 * 2048, (long)1024 * 2048, (long)2048 * 1024, 1.0f, Lrow, nullptr);
}

// Round 8
// 228.145 us; speedup vs baseline: 1.0616x; 1.0180x over previous
//
#include <hip/hip_runtime.h>

typedef __attribute__((ext_vector_type(8))) short short8;
typedef __attribute__((ext_vector_type(8))) unsigned short ushort8;
typedef __attribute__((ext_vector_type(4))) float f32x4;

__device__ __forceinline__ float bf2f(unsigned short u) {
  union { unsigned int u; float f; } c; c.u = ((unsigned int)u) << 16; return c.f;
}
__device__ __forceinline__ unsigned short f2bf(float f) {
  union { float f; unsigned int u; } c; c.f = f;
  unsigned int x = c.u;
  return (unsigned short)((x + 0x7FFFu + ((x >> 16) & 1u)) >> 16);
}

#define GLD_LDS16(g, l)                                                        \
  __builtin_amdgcn_global_load_lds(                                            \
      (const __attribute__((address_space(1))) void*)(g),                      \
      (__attribute__((address_space(3))) void*)(l), 16, 0, 0)

// --------------------------------------------------- fused prep:
// [0,4096): cast X fp32 -> bf16
// [4096,4864): transpose+cast W[1024][3072] -> Wt[3072][1024] bf16
// 4864: zero Lrow
__global__ __launch_bounds__(256) void prep_kernel(
    const float* __restrict__ X, unsigned short* __restrict__ Xb,
    const float* __restrict__ W, unsigned short* __restrict__ Wt,
    float* __restrict__ Lrow) {
  const int t = threadIdx.x;
  if (blockIdx.x < 4096) {
    long i = ((long)blockIdx.x * 256 + t) * 8;
    float4 a = *(const float4*)(X + i);
    float4 b = *(const float4*)(X + i + 4);
    ushort8 o;
    o[0] = f2bf(a.x); o[1] = f2bf(a.y); o[2] = f2bf(a.z); o[3] = f2bf(a.w);
    o[4] = f2bf(b.x); o[5] = f2bf(b.y); o[6] = f2bf(b.z); o[7] = f2bf(b.w);
    *(ushort8*)(Xb + i) = o;
  } else if (blockIdx.x < 4864) {
    const int bid = blockIdx.x - 4096;          // 768 blocks = 48 x 16
    const int f0 = (bid % 48) * 64;
    const int e0 = (bid / 48) * 64;
    __shared__ unsigned short tile[64][65];
    const int cg = (t & 15) * 4;
    const int r = t >> 4;
#pragma unroll
    for (int i = 0; i < 4; ++i) {
      int e = r + i * 16;
      float4 v = *(const float4*)(W + (long)(e0 + e) * 3072 + f0 + cg);
      tile[e][cg + 0] = f2bf(v.x);
      tile[e][cg + 1] = f2bf(v.y);
      tile[e][cg + 2] = f2bf(v.z);
      tile[e][cg + 3] = f2bf(v.w);
    }
    __syncthreads();
#pragma unroll
    for (int i = 0; i < 4; ++i) {
      int f = (t >> 4) + i * 16;
      int e = (t & 15) * 4;
      ushort4 o;
      o.x = tile[e + 0][f];
      o.y = tile[e + 1][f];
      o.z = tile[e + 2][f];
      o.w = tile[e + 3][f];
      *(ushort4*)(Wt + (long)(f0 + f) * 1024 + e0 + e) = o;
    }
  } else {
    float4 z = {0.f, 0.f, 0.f, 0.f};
#pragma unroll
    for (int j = 0; j < 8; ++j) *(float4*)(Lrow + (j * 256 + t) * 4) = z;
  }
}

// ---------------------------------------------------------------- GEMM C = A * B^T
// m97 structure (R0/R7-verified: qkv 58.4-60.9 us, ~876 TF at 2 blk/CU).
// This is the measured best body of the session: all 1-blk/CU big-tile
// schedules (R1-R6) landed at 760-850 TF block-rate; m97's 2-blk/CU
// co-residency (m114 overlap) is the winning mechanism.
// MODE 0 (qkv): bx<16 -> bf16 C to QK; bx>=16 -> transposed bf16 to Vt.
// MODE 1 (score): bf16 exp(acc*alpha) + row-sum atomicAdd into Lrow.
// MODE 2 (out): fp32 store of acc/Lrow[row].
template <int MODE>
__device__ __forceinline__ void gemm_body(
    const unsigned short* __restrict__ A, const unsigned short* __restrict__ B,
    void* __restrict__ Cv, int K, int lda, int ldb, int ldc,
    long sA, long sB, long sC, float alpha, float* __restrict__ Lrow,
    unsigned short* __restrict__ Vt) {
  constexpr int BM = 128, BN = 128, BK = 64;
  __shared__ __align__(16) unsigned short smem[BM * BK + BN * BK];  // 32 KB
  unsigned short* As = smem;
  unsigned short* Bs = smem + BM * BK;

  const int t = threadIdx.x;
  const int lane = t & 63;
  const int wave = t >> 6;
  const int quad = lane >> 4;
  const int mrow = lane & 15;
  const int wm = wave >> 1, wn = wave & 1;

  const int bx = blockIdx.x, by = blockIdx.y;
  const int rowA0 = by * BM;
  const int rowB0 = bx * BN;
  const int b = blockIdx.z;
  const unsigned short* Ab = A + (long)b * sA;
  const unsigned short* Bb = B + (long)b * sB;

  f32x4 acc[4][4];
#pragma unroll
  for (int i = 0; i < 4; ++i)
#pragma unroll
    for (int j = 0; j < 4; ++j) {
      f32x4 z = {0.f, 0.f, 0.f, 0.f};
      acc[i][j] = z;
    }

  const int rbase = wave * 32 + (lane >> 3);
  const int c2 = lane & 7;

  for (int kt = 0; kt < K; kt += BK) {
#pragma unroll
    for (int j = 0; j < 4; ++j) {
      int r = rbase + j * 8;
      int c = c2 ^ (r & 7);
      GLD_LDS16(Ab + (long)(rowA0 + r) * lda + kt + c * 8, As + (wave * 4 + j) * 512);
      GLD_LDS16(Bb + (long)(rowB0 + r) * ldb + kt + c * 8, Bs + (wave * 4 + j) * 512);
    }
    __syncthreads();
#pragma unroll
    for (int ks = 0; ks < 2; ++ks) {
      short8 af[4], bfr[4];
#pragma unroll
      for (int i = 0; i < 4; ++i) {
        int rA = wm * 64 + i * 16 + mrow;
        int cc = ks * 4 + quad;
        af[i] = *(const short8*)(As + (rA * 8 + (cc ^ (rA & 7))) * 8);
        int rB = wn * 64 + i * 16 + mrow;
        bfr[i] = *(const short8*)(Bs + (rB * 8 + (cc ^ (rB & 7))) * 8);
      }
#pragma unroll
      for (int mt = 0; mt < 4; ++mt)
#pragma unroll
        for (int nt = 0; nt < 4; ++nt)
          acc[mt][nt] = __builtin_amdgcn_mfma_f32_16x16x32_bf16(
              af[mt], bfr[nt], acc[mt][nt], 0, 0, 0);
    }
    __syncthreads();
  }

  // epilogue — C/D layout (m89-verified): col = lane&15, row = quad*4 + reg
  const int m_base = rowA0 + wm * 64;
  const int n_base = rowB0 + wn * 64;
  const long cb = (long)b * sC;

  if constexpr (MODE == 0) {
    if (bx < 16) {
      // Q/K columns: plain bf16 write into QK
#pragma unroll
      for (int mt = 0; mt < 4; ++mt)
#pragma unroll
        for (int nt = 0; nt < 4; ++nt)
#pragma unroll
          for (int i = 0; i < 4; ++i) {
            int row = m_base + mt * 16 + quad * 4 + i;
            int col = n_base + nt * 16 + mrow;
            ((unsigned short*)Cv)[cb + (long)row * ldc + col] = f2bf(acc[mt][nt][i]);
          }
    } else {
      // V columns: transpose via LDS (smem = full 128x128 bf16 tile), write Vt.
      // swz(x) = ((x&7)<<4) ^ (((x>>3)&3)<<3) — bits >=3 only, so 4-aligned
      // ushort4 writes and 8-aligned ushort8 reads stay contiguous.
#pragma unroll
      for (int mt = 0; mt < 4; ++mt)
#pragma unroll
        for (int nt = 0; nt < 4; ++nt) {
          int r4 = wm * 64 + mt * 16 + quad * 4;         // 4-aligned tile-local s
          int cL = wn * 64 + nt * 16 + mrow;             // tile-local e
          int swz = ((cL & 7) << 4) ^ (((cL >> 3) & 3) << 3);
          ushort4 pk;
          pk.x = f2bf(acc[mt][nt][0]);
          pk.y = f2bf(acc[mt][nt][1]);
          pk.z = f2bf(acc[mt][nt][2]);
          pk.w = f2bf(acc[mt][nt][3]);
          *(ushort4*)(smem + cL * 128 + (r4 ^ swz)) = pk;
        }
      __syncthreads();
      const int batch = by >> 4;
      const int s_base = (by & 15) * 128;
      const int e_base = (bx - 16) * 128;
      unsigned short* VtB = Vt + (long)batch * 1024 * 2048;
#pragma unroll
      for (int rnd = 0; rnd < 8; ++rnd) {
        int e = (t >> 4) + rnd * 16;
        int s = (t & 15) * 8;
        int swz = ((e & 7) << 4) ^ (((e >> 3) & 3) << 3);
        ushort8 v = *(const ushort8*)(smem + e * 128 + (s ^ swz));
        *(ushort8*)(VtB + (long)(e_base + e) * 2048 + s_base + s) = v;
      }
    }
  } else if constexpr (MODE == 1) {
    // E = exp(acc*alpha), store bf16; accumulate row sums -> Lrow
    float p[4][4];
#pragma unroll
    for (int mt = 0; mt < 4; ++mt)
#pragma unroll
      for (int i = 0; i < 4; ++i) p[mt][i] = 0.f;
#pragma unroll
    for (int mt = 0; mt < 4; ++mt)
#pragma unroll
      for (int nt = 0; nt < 4; ++nt)
#pragma unroll
        for (int i = 0; i < 4; ++i) {
          int row = m_base + mt * 16 + quad * 4 + i;
          int col = n_base + nt * 16 + mrow;
          float e = __expf(acc[mt][nt][i] * alpha);
          ((unsigned short*)Cv)[cb + (long)row * ldc + col] = f2bf(e);
          p[mt][i] += e;
        }
#pragma unroll
    for (int off = 1; off < 16; off <<= 1)
#pragma unroll
      for (int mt = 0; mt < 4; ++mt)
#pragma unroll
        for (int i = 0; i < 4; ++i)
          p[mt][i] += __shfl_xor(p[mt][i], off, 64);
    if (mrow == 0) {
#pragma unroll
      for (int mt = 0; mt < 4; ++mt)
#pragma unroll
        for (int i = 0; i < 4; ++i) {
          int row = m_base + mt * 16 + quad * 4 + i;
          atomicAdd(&Lrow[b * 2048 + row], p[mt][i]);
        }
    }
  } else {
    // fp32 out, scaled by 1/Lrow[row]
#pragma unroll
    for (int mt = 0; mt < 4; ++mt)
#pragma unroll
      for (int i = 0; i < 4; ++i) {
        int row = m_base + mt * 16 + quad * 4 + i;
        float inv = 1.0f / Lrow[b * 2048 + row];
#pragma unroll
        for (int nt = 0; nt < 4; ++nt) {
          int col = n_base + nt * 16 + mrow;
          ((float*)Cv)[cb + (long)row * ldc + col] = acc[mt][nt][i] * inv;
        }
      }
  }
}

// distinct names so rocprof separates the three GEMMs
__global__ __launch_bounds__(256, 2) void qkv_gemm_kernel(
    const unsigned short* __restrict__ A, const unsigned short* __restrict__ B,
    void* __restrict__ Cv, int K, int lda, int ldb, int ldc,
    long sA, long sB, long sC, float alpha, float* __restrict__ Lrow,
    unsigned short* __restrict__ Vt) {
  gemm_body<0>(A, B, Cv, K, lda, ldb, ldc, sA, sB, sC, alpha, Lrow, Vt);
}
__global__ __launch_bounds__(256, 2) void score_gemm_kernel(
    const unsigned short* __restrict__ A, const unsigned short* __restrict__ B,
    void* __restrict__ Cv, int K, int lda, int ldb, int ldc,
    long sA, long sB, long sC, float alpha, float* __restrict__ Lrow,
    unsigned short* __restrict__ Vt) {
  gemm_body<1>(A, B, Cv, K, lda, ldb, ldc, sA, sB, sC, alpha, Lrow, Vt);
}
__global__ __launch_bounds__(256, 2) void out_gemm_kernel(
    const unsigned short* __restrict__ A, const unsigned short* __restrict__ B,
    void* __restrict__ Cv, int K, int lda, int ldb, int ldc,
    long sA, long sB, long sC, float alpha, float* __restrict__ Lrow,
    unsigned short* __restrict__ Vt) {
  gemm_body<2>(A, B, Cv, K, lda, ldb, ldc, sA, sB, sC, alpha, Lrow, Vt);
}

// ---------------------------------------------------------------- launch
extern "C" void kernel_launch(void* const* d_in, const int* in_sizes, int n_in,
                              void* d_out, int out_size, void* d_ws, size_t ws_size,
                              hipStream_t stream) {
  const float* X = (const float*)d_in[0];  // [4,2048,1024] fp32
  const float* W = (const float*)d_in[1];  // [1024,3072] fp32
  float* out = (float*)d_out;              // [4,2048,1024] fp32

  char* ws = (char*)d_ws;
  unsigned short* Xb  = (unsigned short*)(ws);                 // 8192x1024 bf16   (16 MiB)
  unsigned short* Wtb = (unsigned short*)(ws + 16777216);      // 3072x1024 bf16   ( 6 MiB)
  unsigned short* QK  = (unsigned short*)(ws + 23068672);      // 8192x2048 bf16   (32 MiB)
  unsigned short* Vt  = (unsigned short*)(ws + 56623104);      // 4x1024x2048 bf16 (16 MiB)
  unsigned short* Sb  = (unsigned short*)(ws + 73400320);      // 4x2048x2048 bf16 (32 MiB)
  float* Lrow         = (float*)(ws + 106954752);              // 4x2048 fp32      (32 KiB)

  // 1. prep: cast X, transpose W, zero Lrow
  prep_kernel<<<4865, 256, 0, stream>>>(X, Xb, W, Wtb, Lrow);

  // 2. [Q|K] = Xb @ Wtb^T  (bx<16 -> QK, ldc=2048); V -> Vt transposed (bx>=16)
  //    m97 128^2, 24x64 = 1536 blocks = 3 exact rounds @ 2 blk/CU
  qkv_gemm_kernel<<<dim3(24, 64, 1), 256, 0, stream>>>(
      Xb, Wtb, QK, 1024, 1024, 1024, 2048, 0L, 0L, 0L, 1.0f, nullptr, Vt);

  // 3. E = exp(Q @ K^T / 32) per batch [2048 x 2048], K=1024; row sums -> Lrow
  //    m97, 16x16x4 = 1024 blocks = 2 exact rounds (R0-measured best)
  score_gemm_kernel<<<dim3(16, 16, 4), 256, 0, stream>>>(
      QK, QK + 1024, Sb, 1024, 2048, 2048, 2048,
      (long)2048 * 2048, (long)2048 * 2048, (long)2048 * 2048, 0.03125f, Lrow, nullptr);

  // 4. O = (E @ Vt^T) / L  per batch  [2048 x 1024], K=2048 -> fp32 out
  //    m97, 8x16x4 = 512 blocks = 1 exact round
  out_gemm_kernel<<<dim3(8, 16, 4), 256, 0, stream>>>(
      Sb, Vt, out, 2048, 2048, 2048, 1024,
      (long)2048 * 2048, (long)1024 * 2048, (long)2048 * 1024, 1.0f, Lrow, nullptr);
}